// Round 10
// baseline (131.957 us; speedup 1.0000x reference)
//
#include <hip/hip_runtime.h>
#include <hip/hip_bf16.h>
#include <stdint.h>

#define NROW 8192
#define DIM  256
#define BK   32
#define MT   128
#define KSPLIT 8
#define NT   32      // (8192/KSPLIT)/BK

typedef float  f32x4  __attribute__((ext_vector_type(4)));
typedef __bf16 bf16x8 __attribute__((ext_vector_type(8)));
typedef unsigned short ushort8 __attribute__((ext_vector_type(8)));
typedef unsigned short ushort4s __attribute__((ext_vector_type(4)));

// round-to-nearest-even f32 -> bf16 (bit pattern)
__device__ __forceinline__ unsigned short f2bf(float f) {
  union { float f; uint32_t u; } v; v.f = f;
  uint32_t u = v.u;
  return (unsigned short)((u + 0x7FFFu + ((u >> 16) & 1u)) >> 16);
}
__device__ __forceinline__ float bf2f(unsigned short us) {
  union { uint32_t u; float f; } t; t.u = (uint32_t)us << 16; return t.f;
}

__device__ __forceinline__ void gload_lds16(const void* gsrc, void* ldsdst) {
  __builtin_amdgcn_global_load_lds(
      (const __attribute__((address_space(1))) uint32_t*)gsrc,
      (__attribute__((address_space(3))) uint32_t*)ldsdst, 16, 0, 0);
}

// ---------------- K0: d = rsqrt(rowsum(g)); gbf = bf16(g) ----------------
// g reads NON-TEMPORAL (zero reuse) -> keeps 128MB gbf L3-resident for K2.
__global__ __launch_bounds__(256) void k_rowsum_cast(const float* __restrict__ g,
                                                     float* __restrict__ d,
                                                     unsigned short* __restrict__ gbf) {
  int r = blockIdx.x;
  const f32x4* row = (const f32x4*)(g + (size_t)r * NROW);
  unsigned short* grow = gbf + (size_t)r * NROW;
  float s = 0.f;
#pragma unroll
  for (int i = 0; i < 8; ++i) {
    int e4 = threadIdx.x + i * 256;
    f32x4 v = __builtin_nontemporal_load(row + e4);
    s += (v[0] + v[1]) + (v[2] + v[3]);
    ushort4s o;
    o[0] = f2bf(v[0]); o[1] = f2bf(v[1]); o[2] = f2bf(v[2]); o[3] = f2bf(v[3]);
    *(ushort4s*)(grow + e4 * 4) = o;
  }
#pragma unroll
  for (int off = 32; off > 0; off >>= 1) s += __shfl_down(s, off, 64);
  __shared__ float red[4];
  int lane = threadIdx.x & 63, w = threadIdx.x >> 6;
  if (lane == 0) red[w] = s;
  __syncthreads();
  if (threadIdx.x == 0) {
    float t = (red[0] + red[1]) + (red[2] + red[3]);
    d[r] = rsqrtf(t);
  }
}

// ---------------- K1: X[kb][n][kin] = bf16(d_j*h[j][n]) LINEAR, plus Wbf ----------------
__global__ __launch_bounds__(256) void k_buildx(const float* __restrict__ h,
                                                const float* __restrict__ d,
                                                const float* __restrict__ Wm,
                                                unsigned short* __restrict__ X,
                                                unsigned short* __restrict__ Wbf) {
  int bid = blockIdx.x;
  int tid = threadIdx.x;
  if (bid >= 256) {  // W cast: 32 blocks x 2048 elements
    int e0 = (bid - 256) * 2048 + tid * 8;
    float4 w0 = *(const float4*)(Wm + e0);
    float4 w1 = *(const float4*)(Wm + e0 + 4);
    ushort8 o;
    o[0] = f2bf(w0.x); o[1] = f2bf(w0.y); o[2] = f2bf(w0.z); o[3] = f2bf(w0.w);
    o[4] = f2bf(w1.x); o[5] = f2bf(w1.y); o[6] = f2bf(w1.z); o[7] = f2bf(w1.w);
    *(ushort8*)(Wbf + e0) = o;
    return;
  }
  int kb = bid;
  int j0 = kb * 32;
  __shared__ float tile[32][DIM];
  __shared__ float dl[32];
#pragma unroll
  for (int i = 0; i < 8; ++i) {
    int e = i * 256 + tid;
    int rr = e >> 6, c4 = e & 63;
    *(float4*)&tile[rr][c4 * 4] =
        *(const float4*)(h + (size_t)(j0 + rr) * DIM + c4 * 4);
  }
  if (tid < 32) dl[tid] = d[j0 + tid];
  __syncthreads();
  unsigned short outv[32];
#pragma unroll
  for (int kin = 0; kin < 32; ++kin)
    outv[kin] = f2bf(tile[kin][tid] * dl[kin]);
  uint4* dst = (uint4*)(X + (size_t)kb * 8192 + tid * 32);
  const uint4* src = (const uint4*)outv;
  dst[0] = src[0]; dst[1] = src[1]; dst[2] = src[2]; dst[3] = src[3];
}

// ---------------- K2: z_part[ks] = gbf_tile @ X (bf16 partials) ----------------
// MT=128, 512 thr (8 waves 2Mx4N), KSPLIT=8 -> grid 512 = 2 blocks/CU.
// ks = bid&7 == XCD id -> each XCD re-reads only its 512KB X-eighth (L2-resident);
// per-XCD X-L2 traffic halved vs MT=64. B wave-private in VGPRs; A LDS-staged
// (NBUF=4, depth-3 issue, counted vmcnt(10), one barrier/iter). gbf from L3.
__global__ __launch_bounds__(512, 4) void k_gemm1(const unsigned short* __restrict__ gbf,
                                                  const unsigned short* __restrict__ X,
                                                  unsigned short* __restrict__ zpart) {
  int bid = blockIdx.x;
  int mtile = bid >> 3, ks = bid & 7;
  int m0 = mtile * MT;
  int kbase = ks * 1024;

  __shared__ unsigned short A[4][MT][BK];   // 4 bufs x 8KB, piece-swizzled

  int tid = threadIdx.x;
  int lane = tid & 63, w = tid >> 6;
  int wr = w >> 2, wc = w & 3;
  int frow = lane & 15, kgrp = lane >> 4;

  // A staging: thread tid -> row tid>>2, dest piece tid&3 (linear dest).
  int ap = (tid & 3) ^ ((tid >> 3) & 3);   // pre-swizzled source piece
  const unsigned short* asrc = gbf + (size_t)(m0 + (tid >> 2)) * NROW + kbase + ap * 8;
  // B: wave-col wc, lane (frow,kgrp): col = wc*64 + nf*16 + frow, piece kgrp.
  const char* xcol = (const char*)X + (size_t)(ks * 32) * 16384 +
                     (size_t)(wc * 64 + frow) * 64 + kgrp * 16;

  f32x4 acc[4][4];
#pragma unroll
  for (int i = 0; i < 4; ++i)
#pragma unroll
    for (int j = 0; j < 4; ++j) acc[i][j] = (f32x4)0.f;

  auto stageA = [&](int t) {   // t wrapped to [0,NT)
    gload_lds16(asrc + (size_t)t * BK, (char*)&A[0][0][0] + (t & 3) * 8192 + w * 1024);
  };
  auto loadB = [&](int t, bf16x8* dstv) {
    const char* p = xcol + (size_t)t * 16384;
#pragma unroll
    for (int nf = 0; nf < 4; ++nf)
      dstv[nf] = __builtin_bit_cast(bf16x8, *(const ushort8*)(p + nf * 1024));
  };

  // read-side swizzled A piece byte-offset (2-way banks max: free)
  int pidx = (kgrp ^ ((frow >> 1) & 3)) << 4;

  auto compute = [&](int buf, bf16x8* bfr) {
#pragma unroll
    for (int mf = 0; mf < 4; ++mf) {
      const ushort8* pa = (const ushort8*)((const char*)&A[0][0][0] + buf * 8192 +
                                           (wr * 64 + mf * 16 + frow) * 64 + pidx);
      bf16x8 af = __builtin_bit_cast(bf16x8, *pa);
#pragma unroll
      for (int nf = 0; nf < 4; ++nf)
        acc[mf][nf] = __builtin_amdgcn_mfma_f32_16x16x32_bf16(af, bfr[nf], acc[mf][nf], 0, 0, 0);
    }
  };

  bf16x8 b0[4], b1[4];
  stageA(0); stageA(1); stageA(2);
  loadB(0, b0); loadB(1, b1);

  for (int t = 0; t < NT; t += 2) {
    asm volatile("s_waitcnt vmcnt(10)" ::: "memory");
    __builtin_amdgcn_s_barrier();
    stageA((t + 3) & (NT - 1));
    compute(t & 3, b0);
    loadB((t + 2) & (NT - 1), b0);
    asm volatile("s_waitcnt vmcnt(10)" ::: "memory");
    __builtin_amdgcn_s_barrier();
    stageA((t + 4) & (NT - 1));
    compute((t + 1) & 3, b1);
    loadB((t + 3) & (NT - 1), b1);
  }
  asm volatile("s_waitcnt vmcnt(0)" ::: "memory");

  // bf16 partial stores
  unsigned short* zp = zpart + (size_t)ks * NROW * DIM;
#pragma unroll
  for (int mf = 0; mf < 4; ++mf)
#pragma unroll
    for (int nf = 0; nf < 4; ++nf)
#pragma unroll
      for (int r = 0; r < 4; ++r) {
        int row = m0 + wr * 64 + mf * 16 + kgrp * 4 + r;
        int col = wc * 64 + nf * 16 + frow;
        zp[(size_t)row * DIM + col] = f2bf(acc[mf][nf][r]);
      }
}

// ---------------- K3: out = relu((h + d*Σz_part) @ Wbf^T + b) ----------------
__global__ __launch_bounds__(256) void k_out(float* __restrict__ out,
                                             const unsigned short* __restrict__ zpart,
                                             const float* __restrict__ h,
                                             const float* __restrict__ d,
                                             const unsigned short* __restrict__ Wbf,
                                             const float* __restrict__ bias) {
  int m0 = blockIdx.x * 32;
  __shared__ unsigned short agg[32][DIM + 8];
  int tid = threadIdx.x;
#pragma unroll
  for (int i = 0; i < 8; ++i) {
    int e = i * 256 + tid;
    int rr = e >> 6, c4 = e & 63;
    size_t off = (size_t)(m0 + rr) * DIM + c4 * 4;
    float zx = 0.f, zy = 0.f, zz = 0.f, zw = 0.f;
#pragma unroll
    for (int ks = 0; ks < KSPLIT; ++ks) {
      ushort4s zk = *(const ushort4s*)(zpart + (size_t)ks * NROW * DIM + off);
      zx += bf2f(zk[0]); zy += bf2f(zk[1]); zz += bf2f(zk[2]); zw += bf2f(zk[3]);
    }
    float4 hv = *(const float4*)(h + off);
    float dr = d[m0 + rr];
    agg[rr][c4 * 4 + 0] = f2bf(hv.x + dr * zx);
    agg[rr][c4 * 4 + 1] = f2bf(hv.y + dr * zy);
    agg[rr][c4 * 4 + 2] = f2bf(hv.z + dr * zz);
    agg[rr][c4 * 4 + 3] = f2bf(hv.w + dr * zw);
  }
  __syncthreads();

  int lane = tid & 63, w = tid >> 6;
  int frow = lane & 15, kgrp = lane >> 4;
  f32x4 acc[2][4];
#pragma unroll
  for (int i = 0; i < 2; ++i)
#pragma unroll
    for (int j = 0; j < 4; ++j) acc[i][j] = (f32x4)0.f;

#pragma unroll
  for (int t = 0; t < 8; ++t) {
    int k0 = t * 32;
    bf16x8 af[2];
#pragma unroll
    for (int mf = 0; mf < 2; ++mf) {
      const ushort8* p = (const ushort8*)&agg[mf * 16 + frow][k0 + kgrp * 8];
      af[mf] = __builtin_bit_cast(bf16x8, *p);
    }
#pragma unroll
    for (int nf = 0; nf < 4; ++nf) {
      int c = w * 64 + nf * 16 + frow;
      const ushort8* pw = (const ushort8*)(Wbf + (size_t)c * DIM + k0 + kgrp * 8);
      bf16x8 bfr = __builtin_bit_cast(bf16x8, *pw);
#pragma unroll
      for (int mf = 0; mf < 2; ++mf)
        acc[mf][nf] = __builtin_amdgcn_mfma_f32_16x16x32_bf16(af[mf], bfr, acc[mf][nf], 0, 0, 0);
    }
  }

#pragma unroll
  for (int mf = 0; mf < 2; ++mf)
#pragma unroll
    for (int nf = 0; nf < 4; ++nf)
#pragma unroll
      for (int r = 0; r < 4; ++r) {
        int row = m0 + mf * 16 + kgrp * 4 + r;
        int col = w * 64 + nf * 16 + frow;
        float v = acc[mf][nf][r] + bias[col];
        out[(size_t)row * DIM + col] = fmaxf(v, 0.f);
      }
}

extern "C" void kernel_launch(void* const* d_in, const int* in_sizes, int n_in,
                              void* d_out, int out_size, void* d_ws, size_t ws_size,
                              hipStream_t stream) {
  const float* g    = (const float*)d_in[0];
  const float* h    = (const float*)d_in[1];
  const float* Wm   = (const float*)d_in[2];
  const float* bias = (const float*)d_in[3];
  float* out = (float*)d_out;

  char* ws = (char*)d_ws;
  float* dvec           = (float*)ws;                          // 32 KB
  unsigned short* X     = (unsigned short*)(ws + (32 << 10));  // 4 MB, linear [kb][n][kin]
  unsigned short* Wbf   = (unsigned short*)(ws + (32 << 10) + (4 << 20));  // 128 KB
  unsigned short* gbf   = (unsigned short*)(ws + (16 << 20));  // 128 MB bf16 copy of g
  unsigned short* zpart = (unsigned short*)(ws + (160ull << 20));  // 32 MB, 8 bf16 partials

  k_rowsum_cast<<<NROW, 256, 0, stream>>>(g, dvec, gbf);
  k_buildx<<<256 + 32, 256, 0, stream>>>(h, dvec, Wm, X, Wbf);
  k_gemm1<<<(NROW / MT) * KSPLIT, 512, 0, stream>>>(gbf, X, zpart);
  k_out<<<NROW / 32, 256, 0, stream>>>(out, zpart, h, dvec, Wbf, bias);
}

// Round 11
// 123.158 us; speedup vs baseline: 1.0714x; 1.0714x over previous
//
#include <hip/hip_runtime.h>
#include <hip/hip_bf16.h>
#include <stdint.h>

#define NROW 8192
#define DIM  256
#define BK   32
#define MT   64
#define KSPLIT 4
#define NT   64      // (8192/KSPLIT)/BK

typedef float  f32x4  __attribute__((ext_vector_type(4)));
typedef __bf16 bf16x8 __attribute__((ext_vector_type(8)));
typedef unsigned short ushort8 __attribute__((ext_vector_type(8)));
typedef unsigned short ushort4s __attribute__((ext_vector_type(4)));

// round-to-nearest-even f32 -> bf16 (bit pattern)
__device__ __forceinline__ unsigned short f2bf(float f) {
  union { float f; uint32_t u; } v; v.f = f;
  uint32_t u = v.u;
  return (unsigned short)((u + 0x7FFFu + ((u >> 16) & 1u)) >> 16);
}
__device__ __forceinline__ float bf2f(unsigned short us) {
  union { uint32_t u; float f; } t; t.u = (uint32_t)us << 16; return t.f;
}

__device__ __forceinline__ void gload_lds16(const void* gsrc, void* ldsdst) {
  __builtin_amdgcn_global_load_lds(
      (const __attribute__((address_space(1))) uint32_t*)gsrc,
      (__attribute__((address_space(3))) uint32_t*)ldsdst, 16, 0, 0);
}

// ---------------- K0: d = rsqrt(rowsum(g)); gbf = bf16(g) ----------------
// g reads NON-TEMPORAL (zero reuse) -> keeps 128MB gbf L3-resident for K2.
__global__ __launch_bounds__(256) void k_rowsum_cast(const float* __restrict__ g,
                                                     float* __restrict__ d,
                                                     unsigned short* __restrict__ gbf) {
  int r = blockIdx.x;
  const f32x4* row = (const f32x4*)(g + (size_t)r * NROW);
  unsigned short* grow = gbf + (size_t)r * NROW;
  float s = 0.f;
#pragma unroll
  for (int i = 0; i < 8; ++i) {
    int e4 = threadIdx.x + i * 256;
    f32x4 v = __builtin_nontemporal_load(row + e4);
    s += (v[0] + v[1]) + (v[2] + v[3]);
    ushort4s o;
    o[0] = f2bf(v[0]); o[1] = f2bf(v[1]); o[2] = f2bf(v[2]); o[3] = f2bf(v[3]);
    *(ushort4s*)(grow + e4 * 4) = o;
  }
#pragma unroll
  for (int off = 32; off > 0; off >>= 1) s += __shfl_down(s, off, 64);
  __shared__ float red[4];
  int lane = threadIdx.x & 63, w = threadIdx.x >> 6;
  if (lane == 0) red[w] = s;
  __syncthreads();
  if (threadIdx.x == 0) {
    float t = (red[0] + red[1]) + (red[2] + red[3]);
    d[r] = rsqrtf(t);
  }
}

// ---------------- K1: X[kb][n][kin] = bf16(d_j*h[j][n]) LINEAR, plus Wbf ----------------
__global__ __launch_bounds__(256) void k_buildx(const float* __restrict__ h,
                                                const float* __restrict__ d,
                                                const float* __restrict__ Wm,
                                                unsigned short* __restrict__ X,
                                                unsigned short* __restrict__ Wbf) {
  int bid = blockIdx.x;
  int tid = threadIdx.x;
  if (bid >= 256) {  // W cast: 32 blocks x 2048 elements
    int e0 = (bid - 256) * 2048 + tid * 8;
    float4 w0 = *(const float4*)(Wm + e0);
    float4 w1 = *(const float4*)(Wm + e0 + 4);
    ushort8 o;
    o[0] = f2bf(w0.x); o[1] = f2bf(w0.y); o[2] = f2bf(w0.z); o[3] = f2bf(w0.w);
    o[4] = f2bf(w1.x); o[5] = f2bf(w1.y); o[6] = f2bf(w1.z); o[7] = f2bf(w1.w);
    *(ushort8*)(Wbf + e0) = o;
    return;
  }
  int kb = bid;
  int j0 = kb * 32;
  __shared__ float tile[32][DIM];
  __shared__ float dl[32];
#pragma unroll
  for (int i = 0; i < 8; ++i) {
    int e = i * 256 + tid;
    int rr = e >> 6, c4 = e & 63;
    *(float4*)&tile[rr][c4 * 4] =
        *(const float4*)(h + (size_t)(j0 + rr) * DIM + c4 * 4);
  }
  if (tid < 32) dl[tid] = d[j0 + tid];
  __syncthreads();
  unsigned short outv[32];
#pragma unroll
  for (int kin = 0; kin < 32; ++kin)
    outv[kin] = f2bf(tile[kin][tid] * dl[kin]);
  uint4* dst = (uint4*)(X + (size_t)kb * 8192 + tid * 32);
  const uint4* src = (const uint4*)outv;
  dst[0] = src[0]; dst[1] = src[1]; dst[2] = src[2]; dst[3] = src[3];
}

// ---------------- K2: z_part[ks] = gbf_tile @ X (bf16 partials) ----------------
// R9 skeleton (MT=64, KSPLIT=4, 256thr, B-in-VGPR, A LDS NBUF=4 depth-3) +
// STAGGERED K-iteration start: block j on an XCD begins at t0=(bid>>3)&63 and
// wraps, so co-resident blocks read DIFFERENT 16KB X chunks at any instant ->
// L2 banks spread instead of hot-spotted (same for A in L3).
__global__ __launch_bounds__(256, 2) void k_gemm1(const unsigned short* __restrict__ gbf,
                                                  const unsigned short* __restrict__ X,
                                                  unsigned short* __restrict__ zpart) {
  int bid = blockIdx.x;
  int mtile = bid >> 2, ks = bid & 3;
  int m0 = mtile * MT;
  int kbase = ks * 2048;
  int t0 = (bid >> 3) & (NT - 1);   // stagger offset (distinct per block within an XCD)

  __shared__ unsigned short A[4][MT][BK];   // 4 bufs x 4KB, piece-swizzled

  int tid = threadIdx.x;
  int lane = tid & 63, w = tid >> 6;
  int frow = lane & 15, kgrp = lane >> 4;

  int ap = (tid & 3) ^ ((tid >> 3) & 3);
  const unsigned short* asrc = gbf + (size_t)(m0 + (tid >> 2)) * NROW + kbase + ap * 8;
  const char* xcol = (const char*)X + (size_t)(ks * 64) * 16384 +
                     (size_t)(w * 64 + frow) * 64 + kgrp * 16;

  f32x4 acc[4][4];
#pragma unroll
  for (int i = 0; i < 4; ++i)
#pragma unroll
    for (int j = 0; j < 4; ++j) acc[i][j] = (f32x4)0.f;

  auto stageA = [&](int buf, int tk) {   // tk = wrapped k-step index
    gload_lds16(asrc + (size_t)tk * BK, (char*)&A[0][0][0] + buf * 4096 + w * 1024);
  };
  auto loadB = [&](int tk, bf16x8* dstv) {
    const char* p = xcol + (size_t)tk * 16384;
#pragma unroll
    for (int nf = 0; nf < 4; ++nf)
      dstv[nf] = __builtin_bit_cast(bf16x8, *(const ushort8*)(p + nf * 1024));
  };

  int pidx = (kgrp ^ ((frow >> 1) & 3)) << 4;

  auto compute = [&](int buf, bf16x8* bfr) {
#pragma unroll
    for (int mf = 0; mf < 4; ++mf) {
      const ushort8* pa = (const ushort8*)((const char*)&A[0][0][0] + buf * 4096 +
                                           (mf * 16 + frow) * 64 + pidx);
      bf16x8 af = __builtin_bit_cast(bf16x8, *pa);
#pragma unroll
      for (int nf = 0; nf < 4; ++nf)
        acc[mf][nf] = __builtin_amdgcn_mfma_f32_16x16x32_bf16(af, bfr[nf], acc[mf][nf], 0, 0, 0);
    }
  };

  bf16x8 b0[4], b1[4];
  stageA(0, t0);
  stageA(1, (t0 + 1) & (NT - 1));
  stageA(2, (t0 + 2) & (NT - 1));
  loadB(t0, b0);
  loadB((t0 + 1) & (NT - 1), b1);

  for (int t = 0; t < NT; t += 2) {
    asm volatile("s_waitcnt vmcnt(10)" ::: "memory");
    __builtin_amdgcn_s_barrier();
    stageA((t + 3) & 3, (t0 + t + 3) & (NT - 1));
    compute(t & 3, b0);
    loadB((t0 + t + 2) & (NT - 1), b0);
    asm volatile("s_waitcnt vmcnt(10)" ::: "memory");
    __builtin_amdgcn_s_barrier();
    stageA((t + 4) & 3, (t0 + t + 4) & (NT - 1));
    compute((t + 1) & 3, b1);
    loadB((t0 + t + 3) & (NT - 1), b1);
  }
  asm volatile("s_waitcnt vmcnt(0)" ::: "memory");

  // bf16 partial stores
  unsigned short* zp = zpart + (size_t)ks * NROW * DIM;
#pragma unroll
  for (int mf = 0; mf < 4; ++mf)
#pragma unroll
    for (int nf = 0; nf < 4; ++nf)
#pragma unroll
      for (int r = 0; r < 4; ++r) {
        int row = m0 + mf * 16 + kgrp * 4 + r;
        int col = w * 64 + nf * 16 + frow;
        zp[(size_t)row * DIM + col] = f2bf(acc[mf][nf][r]);
      }
}

// ---------------- K3: out = relu((h + d*Σz_part) @ Wbf^T + b) ----------------
__global__ __launch_bounds__(256) void k_out(float* __restrict__ out,
                                             const unsigned short* __restrict__ zpart,
                                             const float* __restrict__ h,
                                             const float* __restrict__ d,
                                             const unsigned short* __restrict__ Wbf,
                                             const float* __restrict__ bias) {
  int m0 = blockIdx.x * 32;
  __shared__ unsigned short agg[32][DIM + 8];
  int tid = threadIdx.x;
#pragma unroll
  for (int i = 0; i < 8; ++i) {
    int e = i * 256 + tid;
    int rr = e >> 6, c4 = e & 63;
    size_t off = (size_t)(m0 + rr) * DIM + c4 * 4;
    float zx = 0.f, zy = 0.f, zz = 0.f, zw = 0.f;
#pragma unroll
    for (int ks = 0; ks < KSPLIT; ++ks) {
      ushort4s zk = *(const ushort4s*)(zpart + (size_t)ks * NROW * DIM + off);
      zx += bf2f(zk[0]); zy += bf2f(zk[1]); zz += bf2f(zk[2]); zw += bf2f(zk[3]);
    }
    float4 hv = *(const float4*)(h + off);
    float dr = d[m0 + rr];
    agg[rr][c4 * 4 + 0] = f2bf(hv.x + dr * zx);
    agg[rr][c4 * 4 + 1] = f2bf(hv.y + dr * zy);
    agg[rr][c4 * 4 + 2] = f2bf(hv.z + dr * zz);
    agg[rr][c4 * 4 + 3] = f2bf(hv.w + dr * zw);
  }
  __syncthreads();

  int lane = tid & 63, w = tid >> 6;
  int frow = lane & 15, kgrp = lane >> 4;
  f32x4 acc[2][4];
#pragma unroll
  for (int i = 0; i < 2; ++i)
#pragma unroll
    for (int j = 0; j < 4; ++j) acc[i][j] = (f32x4)0.f;

#pragma unroll
  for (int t = 0; t < 8; ++t) {
    int k0 = t * 32;
    bf16x8 af[2];
#pragma unroll
    for (int mf = 0; mf < 2; ++mf) {
      const ushort8* p = (const ushort8*)&agg[mf * 16 + frow][k0 + kgrp * 8];
      af[mf] = __builtin_bit_cast(bf16x8, *p);
    }
#pragma unroll
    for (int nf = 0; nf < 4; ++nf) {
      int c = w * 64 + nf * 16 + frow;
      const ushort8* pw = (const ushort8*)(Wbf + (size_t)c * DIM + k0 + kgrp * 8);
      bf16x8 bfr = __builtin_bit_cast(bf16x8, *pw);
#pragma unroll
      for (int mf = 0; mf < 2; ++mf)
        acc[mf][nf] = __builtin_amdgcn_mfma_f32_16x16x32_bf16(af[mf], bfr, acc[mf][nf], 0, 0, 0);
    }
  }

#pragma unroll
  for (int mf = 0; mf < 2; ++mf)
#pragma unroll
    for (int nf = 0; nf < 4; ++nf)
#pragma unroll
      for (int r = 0; r < 4; ++r) {
        int row = m0 + mf * 16 + kgrp * 4 + r;
        int col = w * 64 + nf * 16 + frow;
        float v = acc[mf][nf][r] + bias[col];
        out[(size_t)row * DIM + col] = fmaxf(v, 0.f);
      }
}

extern "C" void kernel_launch(void* const* d_in, const int* in_sizes, int n_in,
                              void* d_out, int out_size, void* d_ws, size_t ws_size,
                              hipStream_t stream) {
  const float* g    = (const float*)d_in[0];
  const float* h    = (const float*)d_in[1];
  const float* Wm   = (const float*)d_in[2];
  const float* bias = (const float*)d_in[3];
  float* out = (float*)d_out;

  char* ws = (char*)d_ws;
  float* dvec           = (float*)ws;                          // 32 KB
  unsigned short* X     = (unsigned short*)(ws + (32 << 10));  // 4 MB, linear [kb][n][kin]
  unsigned short* Wbf   = (unsigned short*)(ws + (32 << 10) + (4 << 20));  // 128 KB
  unsigned short* gbf   = (unsigned short*)(ws + (16 << 20));  // 128 MB bf16 copy of g
  unsigned short* zpart = (unsigned short*)(ws + (160ull << 20));  // 16 MB, 4 bf16 partials

  k_rowsum_cast<<<NROW, 256, 0, stream>>>(g, dvec, gbf);
  k_buildx<<<256 + 32, 256, 0, stream>>>(h, dvec, Wm, X, Wbf);
  k_gemm1<<<(NROW / MT) * KSPLIT, 256, 0, stream>>>(gbf, X, zpart);
  k_out<<<NROW / 32, 256, 0, stream>>>(out, zpart, h, dvec, Wbf, bias);
}

// Round 12
// 122.807 us; speedup vs baseline: 1.0745x; 1.0029x over previous
//
#include <hip/hip_runtime.h>
#include <hip/hip_bf16.h>
#include <stdint.h>

#define NROW 8192
#define DIM  256
#define BK   32
#define MT   64
#define KSPLIT 4
#define NT   64      // (8192/KSPLIT)/BK

typedef float  f32x4  __attribute__((ext_vector_type(4)));
typedef __bf16 bf16x8 __attribute__((ext_vector_type(8)));
typedef unsigned short ushort8 __attribute__((ext_vector_type(8)));
typedef unsigned short ushort4s __attribute__((ext_vector_type(4)));

// round-to-nearest-even f32 -> bf16 (bit pattern)
__device__ __forceinline__ unsigned short f2bf(float f) {
  union { float f; uint32_t u; } v; v.f = f;
  uint32_t u = v.u;
  return (unsigned short)((u + 0x7FFFu + ((u >> 16) & 1u)) >> 16);
}
__device__ __forceinline__ float bf2f(unsigned short us) {
  union { uint32_t u; float f; } t; t.u = (uint32_t)us << 16; return t.f;
}

__device__ __forceinline__ void gload_lds16(const void* gsrc, void* ldsdst) {
  __builtin_amdgcn_global_load_lds(
      (const __attribute__((address_space(1))) uint32_t*)gsrc,
      (__attribute__((address_space(3))) uint32_t*)ldsdst, 16, 0, 0);
}

// ---------------- K0: d = rsqrt(rowsum(g)); gbf = bf16(g) ----------------
// g reads NON-TEMPORAL (zero reuse) -> keeps 128MB gbf L3-resident for K2.
__global__ __launch_bounds__(256) void k_rowsum_cast(const float* __restrict__ g,
                                                     float* __restrict__ d,
                                                     unsigned short* __restrict__ gbf) {
  int r = blockIdx.x;
  const f32x4* row = (const f32x4*)(g + (size_t)r * NROW);
  unsigned short* grow = gbf + (size_t)r * NROW;
  float s = 0.f;
#pragma unroll
  for (int i = 0; i < 8; ++i) {
    int e4 = threadIdx.x + i * 256;
    f32x4 v = __builtin_nontemporal_load(row + e4);
    s += (v[0] + v[1]) + (v[2] + v[3]);
    ushort4s o;
    o[0] = f2bf(v[0]); o[1] = f2bf(v[1]); o[2] = f2bf(v[2]); o[3] = f2bf(v[3]);
    *(ushort4s*)(grow + e4 * 4) = o;
  }
#pragma unroll
  for (int off = 32; off > 0; off >>= 1) s += __shfl_down(s, off, 64);
  __shared__ float red[4];
  int lane = threadIdx.x & 63, w = threadIdx.x >> 6;
  if (lane == 0) red[w] = s;
  __syncthreads();
  if (threadIdx.x == 0) {
    float t = (red[0] + red[1]) + (red[2] + red[3]);
    d[r] = rsqrtf(t);
  }
}

// ---------------- K1: X[kb][n][kin] = bf16(d_j*h[j][n]) LINEAR, plus Wbf ----------------
__global__ __launch_bounds__(256) void k_buildx(const float* __restrict__ h,
                                                const float* __restrict__ d,
                                                const float* __restrict__ Wm,
                                                unsigned short* __restrict__ X,
                                                unsigned short* __restrict__ Wbf) {
  int bid = blockIdx.x;
  int tid = threadIdx.x;
  if (bid >= 256) {  // W cast: 32 blocks x 2048 elements
    int e0 = (bid - 256) * 2048 + tid * 8;
    float4 w0 = *(const float4*)(Wm + e0);
    float4 w1 = *(const float4*)(Wm + e0 + 4);
    ushort8 o;
    o[0] = f2bf(w0.x); o[1] = f2bf(w0.y); o[2] = f2bf(w0.z); o[3] = f2bf(w0.w);
    o[4] = f2bf(w1.x); o[5] = f2bf(w1.y); o[6] = f2bf(w1.z); o[7] = f2bf(w1.w);
    *(ushort8*)(Wbf + e0) = o;
    return;
  }
  int kb = bid;
  int j0 = kb * 32;
  __shared__ float tile[32][DIM];
  __shared__ float dl[32];
#pragma unroll
  for (int i = 0; i < 8; ++i) {
    int e = i * 256 + tid;
    int rr = e >> 6, c4 = e & 63;
    *(float4*)&tile[rr][c4 * 4] =
        *(const float4*)(h + (size_t)(j0 + rr) * DIM + c4 * 4);
  }
  if (tid < 32) dl[tid] = d[j0 + tid];
  __syncthreads();
  unsigned short outv[32];
#pragma unroll
  for (int kin = 0; kin < 32; ++kin)
    outv[kin] = f2bf(tile[kin][tid] * dl[kin]);
  uint4* dst = (uint4*)(X + (size_t)kb * 8192 + tid * 32);
  const uint4* src = (const uint4*)outv;
  dst[0] = src[0]; dst[1] = src[1]; dst[2] = src[2]; dst[3] = src[3];
}

// ---------------- K2: z_part[ks] = gbf_tile @ X (bf16 partials) ----------------
// R9 skeleton (MT=64, KSPLIT=4, 256thr, B-in-VGPR, A LDS NBUF=4 depth-3).
// Single change vs R9: __launch_bounds__(256,4) caps VGPR at 128 ->
// 4 blocks/CU (16 waves, 4/SIMD), LDS 4x16KB=64KB fits. TLP doubles.
__global__ __launch_bounds__(256, 4) void k_gemm1(const unsigned short* __restrict__ gbf,
                                                  const unsigned short* __restrict__ X,
                                                  unsigned short* __restrict__ zpart) {
  int bid = blockIdx.x;
  int mtile = bid >> 2, ks = bid & 3;
  int m0 = mtile * MT;
  int kbase = ks * 2048;

  __shared__ unsigned short A[4][MT][BK];   // 4 bufs x 4KB, piece-swizzled

  int tid = threadIdx.x;
  int lane = tid & 63, w = tid >> 6;
  int frow = lane & 15, kgrp = lane >> 4;

  int ap = (tid & 3) ^ ((tid >> 3) & 3);
  const unsigned short* asrc = gbf + (size_t)(m0 + (tid >> 2)) * NROW + kbase + ap * 8;
  const char* xcol = (const char*)X + (size_t)(ks * 64) * 16384 +
                     (size_t)(w * 64 + frow) * 64 + kgrp * 16;

  f32x4 acc[4][4];
#pragma unroll
  for (int i = 0; i < 4; ++i)
#pragma unroll
    for (int j = 0; j < 4; ++j) acc[i][j] = (f32x4)0.f;

  auto stageA = [&](int t) {
    gload_lds16(asrc + (size_t)t * BK, (char*)&A[0][0][0] + (t & 3) * 4096 + w * 1024);
  };
  auto loadB = [&](int t, bf16x8* dstv) {
    const char* p = xcol + (size_t)t * 16384;
#pragma unroll
    for (int nf = 0; nf < 4; ++nf)
      dstv[nf] = __builtin_bit_cast(bf16x8, *(const ushort8*)(p + nf * 1024));
  };

  int pidx = (kgrp ^ ((frow >> 1) & 3)) << 4;

  auto compute = [&](int buf, bf16x8* bfr) {
#pragma unroll
    for (int mf = 0; mf < 4; ++mf) {
      const ushort8* pa = (const ushort8*)((const char*)&A[0][0][0] + buf * 4096 +
                                           (mf * 16 + frow) * 64 + pidx);
      bf16x8 af = __builtin_bit_cast(bf16x8, *pa);
#pragma unroll
      for (int nf = 0; nf < 4; ++nf)
        acc[mf][nf] = __builtin_amdgcn_mfma_f32_16x16x32_bf16(af, bfr[nf], acc[mf][nf], 0, 0, 0);
    }
  };

  bf16x8 b0[4], b1[4];
  stageA(0); stageA(1); stageA(2);
  loadB(0, b0); loadB(1, b1);

  for (int t = 0; t < NT; t += 2) {
    asm volatile("s_waitcnt vmcnt(10)" ::: "memory");
    __builtin_amdgcn_s_barrier();
    stageA((t + 3) & (NT - 1));
    compute(t & 3, b0);
    loadB((t + 2) & (NT - 1), b0);
    asm volatile("s_waitcnt vmcnt(10)" ::: "memory");
    __builtin_amdgcn_s_barrier();
    stageA((t + 4) & (NT - 1));
    compute((t + 1) & 3, b1);
    loadB((t + 3) & (NT - 1), b1);
  }
  asm volatile("s_waitcnt vmcnt(0)" ::: "memory");

  // bf16 partial stores
  unsigned short* zp = zpart + (size_t)ks * NROW * DIM;
#pragma unroll
  for (int mf = 0; mf < 4; ++mf)
#pragma unroll
    for (int nf = 0; nf < 4; ++nf)
#pragma unroll
      for (int r = 0; r < 4; ++r) {
        int row = m0 + mf * 16 + kgrp * 4 + r;
        int col = w * 64 + nf * 16 + frow;
        zp[(size_t)row * DIM + col] = f2bf(acc[mf][nf][r]);
      }
}

// ---------------- K3: out = relu((h + d*Σz_part) @ Wbf^T + b) ----------------
__global__ __launch_bounds__(256) void k_out(float* __restrict__ out,
                                             const unsigned short* __restrict__ zpart,
                                             const float* __restrict__ h,
                                             const float* __restrict__ d,
                                             const unsigned short* __restrict__ Wbf,
                                             const float* __restrict__ bias) {
  int m0 = blockIdx.x * 32;
  __shared__ unsigned short agg[32][DIM + 8];
  int tid = threadIdx.x;
#pragma unroll
  for (int i = 0; i < 8; ++i) {
    int e = i * 256 + tid;
    int rr = e >> 6, c4 = e & 63;
    size_t off = (size_t)(m0 + rr) * DIM + c4 * 4;
    float zx = 0.f, zy = 0.f, zz = 0.f, zw = 0.f;
#pragma unroll
    for (int ks = 0; ks < KSPLIT; ++ks) {
      ushort4s zk = *(const ushort4s*)(zpart + (size_t)ks * NROW * DIM + off);
      zx += bf2f(zk[0]); zy += bf2f(zk[1]); zz += bf2f(zk[2]); zw += bf2f(zk[3]);
    }
    float4 hv = *(const float4*)(h + off);
    float dr = d[m0 + rr];
    agg[rr][c4 * 4 + 0] = f2bf(hv.x + dr * zx);
    agg[rr][c4 * 4 + 1] = f2bf(hv.y + dr * zy);
    agg[rr][c4 * 4 + 2] = f2bf(hv.z + dr * zz);
    agg[rr][c4 * 4 + 3] = f2bf(hv.w + dr * zw);
  }
  __syncthreads();

  int lane = tid & 63, w = tid >> 6;
  int frow = lane & 15, kgrp = lane >> 4;
  f32x4 acc[2][4];
#pragma unroll
  for (int i = 0; i < 2; ++i)
#pragma unroll
    for (int j = 0; j < 4; ++j) acc[i][j] = (f32x4)0.f;

#pragma unroll
  for (int t = 0; t < 8; ++t) {
    int k0 = t * 32;
    bf16x8 af[2];
#pragma unroll
    for (int mf = 0; mf < 2; ++mf) {
      const ushort8* p = (const ushort8*)&agg[mf * 16 + frow][k0 + kgrp * 8];
      af[mf] = __builtin_bit_cast(bf16x8, *p);
    }
#pragma unroll
    for (int nf = 0; nf < 4; ++nf) {
      int c = w * 64 + nf * 16 + frow;
      const ushort8* pw = (const ushort8*)(Wbf + (size_t)c * DIM + k0 + kgrp * 8);
      bf16x8 bfr = __builtin_bit_cast(bf16x8, *pw);
#pragma unroll
      for (int mf = 0; mf < 2; ++mf)
        acc[mf][nf] = __builtin_amdgcn_mfma_f32_16x16x32_bf16(af[mf], bfr, acc[mf][nf], 0, 0, 0);
    }
  }

#pragma unroll
  for (int mf = 0; mf < 2; ++mf)
#pragma unroll
    for (int nf = 0; nf < 4; ++nf)
#pragma unroll
      for (int r = 0; r < 4; ++r) {
        int row = m0 + mf * 16 + kgrp * 4 + r;
        int col = w * 64 + nf * 16 + frow;
        float v = acc[mf][nf][r] + bias[col];
        out[(size_t)row * DIM + col] = fmaxf(v, 0.f);
      }
}

extern "C" void kernel_launch(void* const* d_in, const int* in_sizes, int n_in,
                              void* d_out, int out_size, void* d_ws, size_t ws_size,
                              hipStream_t stream) {
  const float* g    = (const float*)d_in[0];
  const float* h    = (const float*)d_in[1];
  const float* Wm   = (const float*)d_in[2];
  const float* bias = (const float*)d_in[3];
  float* out = (float*)d_out;

  char* ws = (char*)d_ws;
  float* dvec           = (float*)ws;                          // 32 KB
  unsigned short* X     = (unsigned short*)(ws + (32 << 10));  // 4 MB, linear [kb][n][kin]
  unsigned short* Wbf   = (unsigned short*)(ws + (32 << 10) + (4 << 20));  // 128 KB
  unsigned short* gbf   = (unsigned short*)(ws + (16 << 20));  // 128 MB bf16 copy of g
  unsigned short* zpart = (unsigned short*)(ws + (160ull << 20));  // 16 MB, 4 bf16 partials

  k_rowsum_cast<<<NROW, 256, 0, stream>>>(g, dvec, gbf);
  k_buildx<<<256 + 32, 256, 0, stream>>>(h, dvec, Wm, X, Wbf);
  k_gemm1<<<(NROW / MT) * KSPLIT, 256, 0, stream>>>(gbf, X, zpart);
  k_out<<<NROW / 32, 256, 0, stream>>>(out, zpart, h, dvec, Wbf, bias);
}